// Round 1
// baseline (98.953 us; speedup 1.0000x reference)
//
#include <hip/hip_runtime.h>
#include <math.h>

#define GAMMA_F 0.2f
#define NT 1024          // one block, 16 waves, one CU does everything
#define NB 1024          // value buckets over s in [-0.25, 1.25)
#define CAP 9920         // capacity for compacted negatives (n_neg ~= 8192)
#define DLO 0.25f
#define DSCALE (NB / 1.5f)

__device__ __forceinline__ float sig2(float2 y) {
    // softmax[:,1] = 1 / (1 + exp(y0 - y1))
    return 1.0f / (1.0f + __expf(y.x - y.y));
}

// Monotone bucket map: x <= y  =>  bucket_of(x) <= bucket_of(y)  (f32-safe:
// add, mul-by-positive, floor, clamp are all monotone). Hence
// bucket(b) > bucket(a) => b > a, and b > a => bucket(b) >= bucket(a);
// the == bucket case is resolved exactly with a value compare.
__device__ __forceinline__ int bucket_of(float x) {
    int k = (int)floorf((x + DLO) * DSCALE);
    return k < 0 ? 0 : (k >= NB ? NB - 1 : k);
}

// O(N) softAUC: sum over pos i, neg j with b_j > a_i of (b_j - a_i)^3,
// a = s_pos - gamma, b = s_neg. Factorized via per-bucket suffix power sums:
//   sum_{b>a} (b-a)^3 = S3 - 3a*S2 + 3a^2*S1 - a^3*S0  (Sk over buckets > ka)
// plus an exact element-wise loop over the boundary bucket ka.
extern "C" __global__ __launch_bounds__(NT) void softauc_bucket_kernel(
        const float* __restrict__ y_pred, const int* __restrict__ y_true,
        int n, float* __restrict__ out) {
    __shared__ int cnt[NB];          // negatives per bucket
    __shared__ int cur[NB];          // scan result -> insertion cursor -> bucket end
    __shared__ float negv[CAP];      // bucket-sorted negative scores
    __shared__ float4 ssum[NB];      // exclusive suffix sums (S0,S1,S2,S3) per bucket
    __shared__ int wscan[NT / 64];
    __shared__ double4 wtot[NT / 64];
    __shared__ double wred[NT / 64];
    // LDS total: 4096+4096+39680+16384+64+512+128 = 64960 B (< 64 KiB)

    const float2* __restrict__ yp2 = (const float2*)y_pred;
    int tid = threadIdx.x;
    int lane = tid & 63;
    int wave = tid >> 6;

    cnt[tid] = 0;                    // NB == NT: one bucket per thread
    __syncthreads();

    const int stride4 = NT * 4;
    int nfull = n - (n % stride4);

    // ---- pass 1: histogram negatives (4-row batched loads hide L2 latency) ----
    for (int base = 0; base < nfull; base += stride4) {
        float2 ya = yp2[base + tid];
        float2 yb = yp2[base + NT + tid];
        float2 yc = yp2[base + 2 * NT + tid];
        float2 yd = yp2[base + 3 * NT + tid];
        int ta = y_true[base + tid];
        int tb = y_true[base + NT + tid];
        int tc = y_true[base + 2 * NT + tid];
        int td = y_true[base + 3 * NT + tid];
        if (ta != 1) atomicAdd(&cnt[bucket_of(sig2(ya))], 1);
        if (tb != 1) atomicAdd(&cnt[bucket_of(sig2(yb))], 1);
        if (tc != 1) atomicAdd(&cnt[bucket_of(sig2(yc))], 1);
        if (td != 1) atomicAdd(&cnt[bucket_of(sig2(yd))], 1);
    }
    for (int r = nfull + tid; r < n; r += NT) {
        if (y_true[r] != 1) atomicAdd(&cnt[bucket_of(sig2(yp2[r]))], 1);
    }
    __syncthreads();

    // ---- exclusive prefix scan: cnt -> cur (insertion cursors) ----
    {
        int v = cnt[tid];
        int inc = v;
        #pragma unroll
        for (int d = 1; d < 64; d <<= 1) {
            int t = __shfl_up(inc, d, 64);
            if (lane >= d) inc += t;
        }
        if (lane == 63) wscan[wave] = inc;
        __syncthreads();
        int off = 0;
        for (int w = 0; w < wave; ++w) off += wscan[w];
        cur[tid] = off + inc - v;    // exclusive
    }
    __syncthreads();

    // ---- pass 2: scatter negatives (bucket counting sort into negv) ----
    for (int base = 0; base < nfull; base += stride4) {
        float2 ya = yp2[base + tid];
        float2 yb = yp2[base + NT + tid];
        float2 yc = yp2[base + 2 * NT + tid];
        float2 yd = yp2[base + 3 * NT + tid];
        int ta = y_true[base + tid];
        int tb = y_true[base + NT + tid];
        int tc = y_true[base + 2 * NT + tid];
        int td = y_true[base + 3 * NT + tid];
        if (ta != 1) { float b = sig2(ya); int p = atomicAdd(&cur[bucket_of(b)], 1); if (p < CAP) negv[p] = b; }
        if (tb != 1) { float b = sig2(yb); int p = atomicAdd(&cur[bucket_of(b)], 1); if (p < CAP) negv[p] = b; }
        if (tc != 1) { float b = sig2(yc); int p = atomicAdd(&cur[bucket_of(b)], 1); if (p < CAP) negv[p] = b; }
        if (td != 1) { float b = sig2(yd); int p = atomicAdd(&cur[bucket_of(b)], 1); if (p < CAP) negv[p] = b; }
    }
    for (int r = nfull + tid; r < n; r += NT) {
        if (y_true[r] != 1) { float b = sig2(yp2[r]); int p = atomicAdd(&cur[bucket_of(b)], 1); if (p < CAP) negv[p] = b; }
    }
    __syncthreads();
    // now cur[k] = end of bucket k; begin = cur[k] - cnt[k]

    // ---- phase 3: per-bucket power sums + block-wide EXCLUSIVE SUFFIX scan ----
    // thread tid owns bucket k = NB-1-tid so an ascending-tid exclusive prefix
    // scan yields, for bucket k, the sums over all buckets > k.
    {
        int k = (NB - 1) - tid;
        int e = min(cur[k], CAP);
        int b0 = max(e - cnt[k], 0);
        double c0 = (double)cnt[k], c1 = 0.0, c2 = 0.0, c3 = 0.0;
        for (int i = b0; i < e; ++i) {
            double b = (double)negv[i];
            double b2 = b * b;
            c1 += b; c2 += b2; c3 += b2 * b;
        }
        double i0 = c0, i1 = c1, i2 = c2, i3 = c3;   // wave-inclusive scan
        #pragma unroll
        for (int d = 1; d < 64; d <<= 1) {
            double t0 = __shfl_up(i0, d, 64);
            double t1 = __shfl_up(i1, d, 64);
            double t2 = __shfl_up(i2, d, 64);
            double t3 = __shfl_up(i3, d, 64);
            if (lane >= d) { i0 += t0; i1 += t1; i2 += t2; i3 += t3; }
        }
        if (lane == 63) wtot[wave] = make_double4(i0, i1, i2, i3);
        __syncthreads();
        double o0 = 0.0, o1 = 0.0, o2 = 0.0, o3 = 0.0;
        for (int w = 0; w < wave; ++w) {
            double4 t = wtot[w];
            o0 += t.x; o1 += t.y; o2 += t.z; o3 += t.w;
        }
        // exclusive = wave offset + inclusive - self
        ssum[k] = make_float4((float)(o0 + i0 - c0), (float)(o1 + i1 - c1),
                              (float)(o2 + i2 - c2), (float)(o3 + i3 - c3));
    }
    __syncthreads();

    // ---- pass 3: positives — polynomial on suffix sums + exact boundary bucket ----
    double acc = 0.0;
    for (int base = 0; base < nfull; base += stride4) {
        float2 ya = yp2[base + tid];
        float2 yb = yp2[base + NT + tid];
        float2 yc = yp2[base + 2 * NT + tid];
        float2 yd = yp2[base + 3 * NT + tid];
        int ta = y_true[base + tid];
        int tb = y_true[base + NT + tid];
        int tc = y_true[base + 2 * NT + tid];
        int td = y_true[base + 3 * NT + tid];
        #pragma unroll
        for (int q = 0; q < 4; ++q) {
            int t = (q == 0) ? ta : (q == 1) ? tb : (q == 2) ? tc : td;
            if (t == 1) {
                float2 y = (q == 0) ? ya : (q == 1) ? yb : (q == 2) ? yc : yd;
                float a = sig2(y) - GAMMA_F;
                int ka = bucket_of(a);
                float4 ss = ssum[ka];
                double ad = (double)a;
                acc += (double)ss.w - 3.0 * ad * (double)ss.z
                     + 3.0 * ad * ad * (double)ss.y - ad * ad * ad * (double)ss.x;
                int e = min(cur[ka], CAP);
                int b0 = max(e - cnt[ka], 0);
                for (int i = b0; i < e; ++i) {
                    float b = negv[i];
                    if (b > a) {             // exact strict compare, matches diff<0
                        double tt = (double)b - ad;
                        acc += tt * tt * tt;
                    }
                }
            }
        }
    }
    for (int r = nfull + tid; r < n; r += NT) {
        if (y_true[r] == 1) {
            float a = sig2(yp2[r]) - GAMMA_F;
            int ka = bucket_of(a);
            float4 ss = ssum[ka];
            double ad = (double)a;
            acc += (double)ss.w - 3.0 * ad * (double)ss.z
                 + 3.0 * ad * ad * (double)ss.y - ad * ad * ad * (double)ss.x;
            int e = min(cur[ka], CAP);
            int b0 = max(e - cnt[ka], 0);
            for (int i = b0; i < e; ++i) {
                float b = negv[i];
                if (b > a) {
                    double tt = (double)b - ad;
                    acc += tt * tt * tt;
                }
            }
        }
    }

    // ---- block reduce, single plain store (no atomic, poison overwritten) ----
    #pragma unroll
    for (int off = 32; off > 0; off >>= 1) acc += __shfl_down(acc, off, 64);
    if (lane == 0) wred[wave] = acc;
    __syncthreads();
    if (tid == 0) {
        double t = 0.0;
        #pragma unroll
        for (int w = 0; w < NT / 64; ++w) t += wred[w];
        out[0] = (float)t;
    }
}

extern "C" void kernel_launch(void* const* d_in, const int* in_sizes, int n_in,
                              void* d_out, int out_size, void* d_ws, size_t ws_size,
                              hipStream_t stream) {
    const float* y_pred = (const float*)d_in[0];
    const int* y_true = (const int*)d_in[1];
    int n = in_sizes[1];  // N; y_pred has 2N floats
    float* out = (float*)d_out;
    (void)d_ws; (void)ws_size; (void)n_in; (void)out_size;

    dim3 grid(1), block(NT);
    softauc_bucket_kernel<<<grid, block, 0, stream>>>(y_pred, y_true, n, out);
}

// Round 2
// 91.855 us; speedup vs baseline: 1.0773x; 1.0773x over previous
//
#include <hip/hip_runtime.h>
#include <math.h>

#define GAMMA_F 0.2f
#define K1_BS 256        // K1 block size = segment capacity
#define MAXSEG 256       // max K1 blocks (n <= 65536)
#define NT 1024          // K2: one block, 16 waves
#define NB 512           // value buckets over s in [-0.25, 1.25)
#define CAP 8960         // compacted-negative capacity (n_neg ~ 8192, +12 sigma)
#define DLO 0.25f
#define DSCALE (NB / 1.5f)

__device__ __forceinline__ float sig2(float2 y) {
    // softmax[:,1] = 1 / (1 + exp(y0 - y1))
    return 1.0f / (1.0f + __expf(y.x - y.y));
}

// Monotone bucket map (add, mul-by-positive, floor, clamp are all monotone):
// bucket(b) > bucket(a) => b > a;  b > a => bucket(b) >= bucket(a).
// The == bucket case is resolved exactly with a value compare in K2.
__device__ __forceinline__ int bucket_of(float x) {
    int k = (int)floorf((x + DLO) * DSCALE);
    return k < 0 ? 0 : (k >= NB ? NB - 1 : k);
}

// ---- K1: whole-chip pass. Sigmoid once per element; ballot-compact into
// per-block segments (deterministic slots -> no global atomics, no memset). ----
extern "C" __global__ __launch_bounds__(K1_BS) void k1_compact(
        const float* __restrict__ y_pred, const int* __restrict__ y_true, int n,
        int* __restrict__ pcnt, int* __restrict__ ncnt,
        float* __restrict__ posv, float* __restrict__ negraw) {
    __shared__ int lc[2];
    int tid = threadIdx.x, lane = tid & 63;
    if (tid < 2) lc[tid] = 0;
    __syncthreads();

    int i = blockIdx.x * K1_BS + tid;
    float s = 0.0f;
    bool isp = false, isn = false;
    if (i < n) {
        float2 y = ((const float2*)y_pred)[i];   // coalesced 8B/lane
        s = sig2(y);
        isp = (y_true[i] == 1);
        isn = !isp;
    }
    unsigned long long lt = (1ULL << lane) - 1ULL;
    int segbase = blockIdx.x * K1_BS;
    {
        unsigned long long m = __ballot(isp);
        int base = 0;
        if (lane == 0) base = atomicAdd(&lc[0], __popcll(m));
        base = __shfl(base, 0, 64);
        if (isp) posv[segbase + base + __popcll(m & lt)] = s - GAMMA_F;
    }
    {
        unsigned long long m = __ballot(isn);
        int base = 0;
        if (lane == 0) base = atomicAdd(&lc[1], __popcll(m));
        base = __shfl(base, 0, 64);
        if (isn) negraw[segbase + base + __popcll(m & lt)] = s;
    }
    __syncthreads();
    if (tid == 0) { pcnt[blockIdx.x] = lc[0]; ncnt[blockIdx.x] = lc[1]; }
}

// ---- K2: single block. Histogram -> scan -> counting sort -> f64 suffix
// power sums -> positives: Horner polynomial + exact f32 boundary bucket. ----
extern "C" __global__ __launch_bounds__(NT) void k2_reduce(
        int nseg,
        const int* __restrict__ pcnt, const int* __restrict__ ncnt,
        const float* __restrict__ posv, const float* __restrict__ negraw,
        float* __restrict__ out) {
    __shared__ int scp[MAXSEG], scn[MAXSEG];
    __shared__ int cnt[NB], cur[NB];
    __shared__ float negv[CAP];
    __shared__ double4 ssum[NB];     // (S0, 3*S1, 3*S2, S3) exclusive suffix sums
    __shared__ int wscan[8];
    __shared__ double4 wtot[8];
    __shared__ double wred[NT / 64];
    // LDS: 1024+1024+2048+2048+35840+16384+32+256+128 = 58784 B (< 64 KiB)

    int tid = threadIdx.x, lane = tid & 63, w = tid >> 6;

    if (tid < MAXSEG) {
        bool in = (tid < nseg);
        scp[tid] = in ? pcnt[tid] : 0;
        scn[tid] = in ? ncnt[tid] : 0;
    }
    if (tid < NB) cnt[tid] = 0;
    __syncthreads();

    // histogram negatives (wave-strided segments)
    for (int s = w; s < nseg; s += NT / 64) {
        int c = scn[s];
        const float* seg = negraw + s * K1_BS;
        for (int i = lane; i < c; i += 64)
            atomicAdd(&cnt[bucket_of(seg[i])], 1);
    }
    __syncthreads();

    // exclusive prefix scan: cnt -> cur (insertion cursors), NB=512 (waves 0-7)
    {
        int v = (tid < NB) ? cnt[tid] : 0;
        int inc = v;
        #pragma unroll
        for (int d = 1; d < 64; d <<= 1) {
            int t = __shfl_up(inc, d, 64);
            if (lane >= d) inc += t;
        }
        if (tid < NB && lane == 63) wscan[w] = inc;
        __syncthreads();
        if (tid < NB) {
            int off = 0;
            for (int ww = 0; ww < w; ++ww) off += wscan[ww];
            cur[tid] = off + inc - v;
        }
    }
    __syncthreads();

    // scatter (bucket counting sort): cur[k] becomes end of bucket k
    for (int s = w; s < nseg; s += NT / 64) {
        int c = scn[s];
        const float* seg = negraw + s * K1_BS;
        for (int i = lane; i < c; i += 64) {
            float b = seg[i];
            int p = atomicAdd(&cur[bucket_of(b)], 1);
            if (p < CAP) negv[p] = b;
        }
    }
    __syncthreads();

    // per-bucket f64 power sums + block-wide EXCLUSIVE SUFFIX scan.
    // thread tid owns bucket k = NB-1-tid; ascending-tid exclusive prefix scan
    // == sums over all buckets > k.
    {
        double c0 = 0.0, c1 = 0.0, c2 = 0.0, c3 = 0.0;
        if (tid < NB) {
            int k = (NB - 1) - tid;
            int e = min(cur[k], CAP);
            int b0 = max(e - cnt[k], 0);
            c0 = (double)cnt[k];
            for (int i = b0; i < e; ++i) {
                double b = (double)negv[i];
                double b2 = b * b;
                c1 += b; c2 += b2; c3 += b2 * b;
            }
        }
        double i0 = c0, i1 = c1, i2 = c2, i3 = c3;
        #pragma unroll
        for (int d = 1; d < 64; d <<= 1) {
            double t0 = __shfl_up(i0, d, 64);
            double t1 = __shfl_up(i1, d, 64);
            double t2 = __shfl_up(i2, d, 64);
            double t3 = __shfl_up(i3, d, 64);
            if (lane >= d) { i0 += t0; i1 += t1; i2 += t2; i3 += t3; }
        }
        if (tid < NB && lane == 63) wtot[w] = make_double4(i0, i1, i2, i3);
        __syncthreads();
        if (tid < NB) {
            double o0 = 0.0, o1 = 0.0, o2 = 0.0, o3 = 0.0;
            for (int ww = 0; ww < w; ++ww) {
                double4 t = wtot[ww];
                o0 += t.x; o1 += t.y; o2 += t.z; o3 += t.w;
            }
            int k = (NB - 1) - tid;
            // exclusive = wave offset + inclusive - self; premultiply 3 for Horner
            ssum[k] = make_double4(o0 + i0 - c0, 3.0 * (o1 + i1 - c1),
                                   3.0 * (o2 + i2 - c2), o3 + i3 - c3);
        }
    }
    __syncthreads();

    // positives: sum_{b>a}(b-a)^3 = S3 - 3a*S2 + 3a^2*S1 - a^3*S0 over buckets
    // > ka (Horner, 3 f64 FMAs) + exact boundary bucket in f32 (each term
    // <= bucketwidth^3 ~ 2.5e-8, so f32 abs error is far below output ulp).
    double acc = 0.0;
    float accf = 0.0f;
    for (int s = w; s < nseg; s += NT / 64) {
        int c = scp[s];
        const float* seg = posv + s * K1_BS;
        for (int i = lane; i < c; i += 64) {
            float a = seg[i];
            int ka = bucket_of(a);
            double4 ss = ssum[ka];
            double ad = (double)a;
            double p1 = fma(-ad, ss.x, ss.y);   // -a*S0 + 3S1
            double p2 = fma(ad, p1, -ss.z);     //  a*p1 - 3S2
            acc += fma(ad, p2, ss.w);           //  a*p2 + S3
            int e = min(cur[ka], CAP);
            int b0 = max(e - cnt[ka], 0);
            for (int ii = b0; ii < e; ++ii) {
                float t = fmaxf(negv[ii] - a, 0.0f);  // exact strict compare
                accf += (t * t) * t;
            }
        }
    }
    acc += (double)accf;

    // block reduce -> single plain store (overwrites out poison)
    #pragma unroll
    for (int off = 32; off > 0; off >>= 1) acc += __shfl_down(acc, off, 64);
    if (lane == 0) wred[w] = acc;
    __syncthreads();
    if (tid == 0) {
        double t = 0.0;
        #pragma unroll
        for (int ww = 0; ww < NT / 64; ++ww) t += wred[ww];
        out[0] = (float)t;
    }
}

extern "C" void kernel_launch(void* const* d_in, const int* in_sizes, int n_in,
                              void* d_out, int out_size, void* d_ws, size_t ws_size,
                              hipStream_t stream) {
    const float* y_pred = (const float*)d_in[0];
    const int* y_true = (const int*)d_in[1];
    int n = in_sizes[1];  // N; y_pred has 2N floats
    float* out = (float*)d_out;
    (void)n_in; (void)out_size; (void)ws_size;

    int nseg = (n + K1_BS - 1) / K1_BS;
    if (nseg > MAXSEG) nseg = MAXSEG;   // N=16384 -> 64 segments

    int* pcnt = (int*)d_ws;
    int* ncnt = pcnt + MAXSEG;
    float* posv = (float*)(ncnt + MAXSEG);
    float* negraw = posv + MAXSEG * K1_BS;

    k1_compact<<<dim3(nseg), dim3(K1_BS), 0, stream>>>(y_pred, y_true, n,
                                                       pcnt, ncnt, posv, negraw);
    k2_reduce<<<dim3(1), dim3(NT), 0, stream>>>(nseg, pcnt, ncnt, posv, negraw,
                                                (float*)out);
}

// Round 3
// 68.728 us; speedup vs baseline: 1.4398x; 1.3365x over previous
//
#include <hip/hip_runtime.h>
#include <math.h>

#define GAMMA_F 0.2f
#define NT 1024          // one block, 16 waves — the whole job
#define NB 512           // value buckets over x in [-0.25, 1.25)
#define DLO 0.25f
#define DSCALE (NB / 1.5f)

__device__ __forceinline__ float sig2(float2 y) {
    // softmax[:,1] = 1 / (1 + exp(y0 - y1))
    return 1.0f / (1.0f + __expf(y.x - y.y));
}

// Monotone bucket map (add, mul-by-positive, floor, clamp are all monotone):
// bucket(b) > bucket(a) => b > a  (exact subset of the reference's diff<0 set).
// Same-bucket b>a pairs are DROPPED: each term <= width^3 = 2.5e-8, ~2e5 such
// pairs -> abs error <= ~5e-3 on a ~6.8e6 result (7e-10 relative, far below
// one f32 ulp of the output).
__device__ __forceinline__ int bucket_of(float x) {
    int k = (int)floorf((x + DLO) * DSCALE);
    return k < 0 ? 0 : (k >= NB ? NB - 1 : k);
}

// Factorized O(N) softAUC, fully fused in ONE single-block kernel:
//   sum_{kb>ka} (b-a)^3 = sum_k [SN3(k)P0(k) - 3 SN2(k)P1(k) + 3 SN1(k)P2(k)
//                                - SN0(k)P3(k)]
// with Pj(k) = sum of a^j over positives in bucket k (a = s - gamma),
//      Nj(k) = sum of b^j over negatives in bucket k (b = s),
//      SNj(k) = exclusive suffix sums of Nj over buckets > k.
// One pass over the input: sigmoid once, 4x f64 LDS atomicAdd per element.
// Then a 512-wide f64 suffix scan + dot product. No sort, no boundary loops,
// no workspace, no second dispatch.
extern "C" __global__ __launch_bounds__(NT) void softauc_onepass(
        const float* __restrict__ y_pred, const int* __restrict__ y_true,
        int n, float* __restrict__ out) {
    // S layout: class 0 (pos) at [j*NB + k], class 1 (neg) at [4*NB + j*NB + k]
    __shared__ double S[8 * NB];          // 32 KiB of f64 power sums
    __shared__ double4 wtot[NT / 64];
    __shared__ double wred[NT / 64];

    int tid = threadIdx.x, lane = tid & 63, w = tid >> 6;

    for (int i = tid; i < 8 * NB; i += NT) S[i] = 0.0;
    __syncthreads();

    const float2* __restrict__ yp2 = (const float2*)y_pred;
    const int stride4 = NT * 4;
    int nfull = n - (n % stride4);

    // ---- single input pass: 4-batched loads hide L2 latency ----
    for (int base = 0; base < nfull; base += stride4) {
        float2 ya = yp2[base + tid];
        float2 yb = yp2[base + NT + tid];
        float2 yc = yp2[base + 2 * NT + tid];
        float2 yd = yp2[base + 3 * NT + tid];
        int ta = y_true[base + tid];
        int tb = y_true[base + NT + tid];
        int tc = y_true[base + 2 * NT + tid];
        int td = y_true[base + 3 * NT + tid];
        #pragma unroll
        for (int q = 0; q < 4; ++q) {
            float2 y = (q == 0) ? ya : (q == 1) ? yb : (q == 2) ? yc : yd;
            int t = (q == 0) ? ta : (q == 1) ? tb : (q == 2) ? tc : td;
            float s = sig2(y);
            bool isp = (t == 1);
            float x = isp ? s - GAMMA_F : s;   // pos uses a = s - gamma
            int off0 = (isp ? 0 : 4 * NB) + bucket_of(x);
            double d = (double)x, d2 = d * d;
            atomicAdd(&S[off0], 1.0);              // branch-free class select:
            atomicAdd(&S[off0 + NB], d);           // all lanes issue the same 4
            atomicAdd(&S[off0 + 2 * NB], d2);      // ds_add_f64 instructions
            atomicAdd(&S[off0 + 3 * NB], d2 * d);
        }
    }
    for (int r = nfull + tid; r < n; r += NT) {
        float2 y = yp2[r];
        float s = sig2(y);
        bool isp = (y_true[r] == 1);
        float x = isp ? s - GAMMA_F : s;
        int off0 = (isp ? 0 : 4 * NB) + bucket_of(x);
        double d = (double)x, d2 = d * d;
        atomicAdd(&S[off0], 1.0);
        atomicAdd(&S[off0 + NB], d);
        atomicAdd(&S[off0 + 2 * NB], d2);
        atomicAdd(&S[off0 + 3 * NB], d2 * d);
    }
    __syncthreads();

    // ---- exclusive SUFFIX scan of neg power sums + dot with pos sums ----
    // thread tid owns bucket k = NB-1-tid; ascending-tid exclusive prefix scan
    // == sums over all buckets > k. Waves 8-15 carry zeros.
    int k = (NB - 1) - tid;
    double c0 = 0.0, c1 = 0.0, c2 = 0.0, c3 = 0.0;
    if (tid < NB) {
        c0 = S[4 * NB + k];
        c1 = S[5 * NB + k];
        c2 = S[6 * NB + k];
        c3 = S[7 * NB + k];
    }
    double i0 = c0, i1 = c1, i2 = c2, i3 = c3;   // wave-inclusive scan
    #pragma unroll
    for (int d = 1; d < 64; d <<= 1) {
        double t0 = __shfl_up(i0, d, 64);
        double t1 = __shfl_up(i1, d, 64);
        double t2 = __shfl_up(i2, d, 64);
        double t3 = __shfl_up(i3, d, 64);
        if (lane >= d) { i0 += t0; i1 += t1; i2 += t2; i3 += t3; }
    }
    if (lane == 63) wtot[w] = make_double4(i0, i1, i2, i3);
    __syncthreads();

    double term = 0.0;
    if (tid < NB) {
        double o0 = 0.0, o1 = 0.0, o2 = 0.0, o3 = 0.0;
        for (int ww = 0; ww < w; ++ww) {
            double4 t = wtot[ww];
            o0 += t.x; o1 += t.y; o2 += t.z; o3 += t.w;
        }
        // exclusive suffix sums for bucket k
        double e0 = o0 + i0 - c0;
        double e1 = o1 + i1 - c1;
        double e2 = o2 + i2 - c2;
        double e3 = o3 + i3 - c3;
        double P0 = S[k], P1 = S[NB + k], P2 = S[2 * NB + k], P3 = S[3 * NB + k];
        term = e3 * P0 - 3.0 * e2 * P1 + 3.0 * e1 * P2 - e0 * P3;
    }

    // ---- block reduce -> single plain store (overwrites out poison) ----
    #pragma unroll
    for (int off = 32; off > 0; off >>= 1) term += __shfl_down(term, off, 64);
    if (lane == 0) wred[w] = term;
    __syncthreads();
    if (tid == 0) {
        double t = 0.0;
        #pragma unroll
        for (int ww = 0; ww < NT / 64; ++ww) t += wred[ww];
        out[0] = (float)t;
    }
}

extern "C" void kernel_launch(void* const* d_in, const int* in_sizes, int n_in,
                              void* d_out, int out_size, void* d_ws, size_t ws_size,
                              hipStream_t stream) {
    const float* y_pred = (const float*)d_in[0];
    const int* y_true = (const int*)d_in[1];
    int n = in_sizes[1];  // N; y_pred has 2N floats
    float* out = (float*)d_out;
    (void)n_in; (void)out_size; (void)d_ws; (void)ws_size;

    softauc_onepass<<<dim3(1), dim3(NT), 0, stream>>>(y_pred, y_true, n, out);
}

// Round 4
// 68.103 us; speedup vs baseline: 1.4530x; 1.0092x over previous
//
#include <hip/hip_runtime.h>
#include <math.h>

#define GAMMA_F 0.2f
#define K1_BS 1024       // K1: one element per thread, 16 blocks for N=16384
#define NT 1024          // K2: single block, 16 waves
#define NB 512           // value buckets over x in [-0.25, 1.25)
#define NH (8 * NB)      // 8 histograms (pos/neg x powers 0..3)
#define DLO 0.25f
#define DSCALE (NB / 1.5f)
#define SCALE 1.099511627776e12    // 2^40 fixed-point scale
#define INV_SCALE (1.0 / 1.099511627776e12)

__device__ __forceinline__ float sig2(float2 y) {
    // softmax[:,1] = 1 / (1 + exp(y0 - y1))
    return 1.0f / (1.0f + __expf(y.x - y.y));
}

// Monotone bucket map: bucket(b) > bucket(a) => b > a (exact subset of the
// reference's diff<0 set). Same-bucket pairs are dropped: each term <=
// width^3 ~ 2.5e-8, ~2e5 pairs -> abs error ~5e-3 on a ~6.8e6 result --
// far below one f32 ulp of the output (proven absmax 0.0 in rounds 1-3).
__device__ __forceinline__ int bucket_of(float x) {
    int k = (int)floorf((x + DLO) * DSCALE);
    return k < 0 ? 0 : (k >= NB ? NB - 1 : k);
}

// ---- K1: 16-CU histogram pass. Powers in f64, accumulated as 2^40
// fixed-point i64 via NATIVE ds_add_u64 (no f64-CAS loops). Each block dumps
// its private 32 KB histogram with plain coalesced stores (no zero-init of
// workspace, no global atomics). Layout: pos powers j at [j*NB+k], neg at
// [4*NB + j*NB + k]; count stored pre-scaled by 2^40 like the rest. ----
extern "C" __global__ __launch_bounds__(K1_BS) void k1_hist(
        const float* __restrict__ y_pred, const int* __restrict__ y_true,
        int n, unsigned long long* __restrict__ part) {
    __shared__ unsigned long long H[NH];   // 32 KiB
    int tid = threadIdx.x;
    for (int i = tid; i < NH; i += K1_BS) H[i] = 0ULL;
    __syncthreads();

    int i = blockIdx.x * K1_BS + tid;
    if (i < n) {
        float2 y = ((const float2*)y_pred)[i];   // coalesced 8B/lane
        float s = sig2(y);
        bool isp = (y_true[i] == 1);
        float x = isp ? s - GAMMA_F : s;         // pos uses a = s - gamma
        int off0 = (isp ? 0 : 4 * NB) + bucket_of(x);
        double d = (double)x, d2 = d * d;
        atomicAdd(&H[off0],          (unsigned long long)(long long)SCALE);
        atomicAdd(&H[off0 + NB],     (unsigned long long)(long long)(d * SCALE));
        atomicAdd(&H[off0 + 2 * NB], (unsigned long long)(long long)(d2 * SCALE));
        atomicAdd(&H[off0 + 3 * NB], (unsigned long long)(long long)(d2 * d * SCALE));
    }
    __syncthreads();

    unsigned long long* dst = part + (size_t)blockIdx.x * NH;
    for (int j = tid; j < NH; j += K1_BS) dst[j] = H[j];
}

// ---- K2: single block. Integer-sum the partial histograms (coalesced),
// convert to f64, exclusive SUFFIX scan of neg power sums, dot with pos
// power sums:
//   sum_{kb>ka}(b-a)^3 = sum_k [SN3 P0 - 3 SN2 P1 + 3 SN1 P2 - SN0 P3](k)
// then block-reduce and one plain store (overwrites the out poison). ----
extern "C" __global__ __launch_bounds__(NT) void k2_reduce(
        int nblk, const unsigned long long* __restrict__ part,
        float* __restrict__ out) {
    __shared__ double H[NH];               // 32 KiB
    __shared__ double4 wtot[NT / 64];
    __shared__ double wred[NT / 64];

    int tid = threadIdx.x, lane = tid & 63, w = tid >> 6;

    // sum partials: per i-slice, thread tid reads part[b*NH + i] -- coalesced
    for (int i = tid; i < NH; i += NT) {
        unsigned long long s = 0ULL;
        #pragma unroll 4
        for (int b = 0; b < nblk; ++b) s += part[(size_t)b * NH + i];
        H[i] = (double)(long long)s * INV_SCALE;
    }
    __syncthreads();

    // exclusive suffix scan of neg sums: thread tid owns bucket k = NB-1-tid;
    // ascending-tid exclusive prefix scan == sums over all buckets > k.
    int k = (NB - 1) - tid;
    double c0 = 0.0, c1 = 0.0, c2 = 0.0, c3 = 0.0;
    if (tid < NB) {
        c0 = H[4 * NB + k];
        c1 = H[5 * NB + k];
        c2 = H[6 * NB + k];
        c3 = H[7 * NB + k];
    }
    double i0 = c0, i1 = c1, i2 = c2, i3 = c3;   // wave-inclusive scan
    #pragma unroll
    for (int d = 1; d < 64; d <<= 1) {
        double t0 = __shfl_up(i0, d, 64);
        double t1 = __shfl_up(i1, d, 64);
        double t2 = __shfl_up(i2, d, 64);
        double t3 = __shfl_up(i3, d, 64);
        if (lane >= d) { i0 += t0; i1 += t1; i2 += t2; i3 += t3; }
    }
    if (lane == 63) wtot[w] = make_double4(i0, i1, i2, i3);
    __syncthreads();

    double term = 0.0;
    if (tid < NB) {
        double o0 = 0.0, o1 = 0.0, o2 = 0.0, o3 = 0.0;
        for (int ww = 0; ww < w; ++ww) {
            double4 t = wtot[ww];
            o0 += t.x; o1 += t.y; o2 += t.z; o3 += t.w;
        }
        double e0 = o0 + i0 - c0;   // exclusive suffix sums for bucket k
        double e1 = o1 + i1 - c1;
        double e2 = o2 + i2 - c2;
        double e3 = o3 + i3 - c3;
        double P0 = H[k], P1 = H[NB + k], P2 = H[2 * NB + k], P3 = H[3 * NB + k];
        term = e3 * P0 - 3.0 * e2 * P1 + 3.0 * e1 * P2 - e0 * P3;
    }

    #pragma unroll
    for (int off = 32; off > 0; off >>= 1) term += __shfl_down(term, off, 64);
    if (lane == 0) wred[w] = term;
    __syncthreads();
    if (tid == 0) {
        double t = 0.0;
        #pragma unroll
        for (int ww = 0; ww < NT / 64; ++ww) t += wred[ww];
        out[0] = (float)t;
    }
}

extern "C" void kernel_launch(void* const* d_in, const int* in_sizes, int n_in,
                              void* d_out, int out_size, void* d_ws, size_t ws_size,
                              hipStream_t stream) {
    const float* y_pred = (const float*)d_in[0];
    const int* y_true = (const int*)d_in[1];
    int n = in_sizes[1];  // N; y_pred has 2N floats
    float* out = (float*)d_out;
    (void)n_in; (void)out_size; (void)ws_size;

    int nblk = (n + K1_BS - 1) / K1_BS;   // 16 for N=16384
    unsigned long long* part = (unsigned long long*)d_ws;  // nblk*32 KiB used

    k1_hist<<<dim3(nblk), dim3(K1_BS), 0, stream>>>(y_pred, y_true, n, part);
    k2_reduce<<<dim3(1), dim3(NT), 0, stream>>>(nblk, part, out);
}